// Round 7
// baseline (94.523 us; speedup 1.0000x reference)
//
#include <hip/hip_runtime.h>
#include <hip/hip_bf16.h>

#define TT 512
#define XS 520      // xbuf (f32) stride: 4-halo | 512 | 4-halo
#define XH 4
#define TS 528      // f16 buffer row stride: 8-halo | 512 | 8-halo
#define HO 8
#define NCH 10
#define K_FC 5120

typedef _Float16 hh2 __attribute__((ext_vector_type(2)));
typedef _Float16 h8 __attribute__((ext_vector_type(8)));
typedef float f32x16 __attribute__((ext_vector_type(16)));
typedef __attribute__((address_space(1))) const void GAS;
typedef __attribute__((address_space(3))) void LAS;

__device__ __forceinline__ float rlf(float v, int l) {
    return __uint_as_float(__builtin_amdgcn_readlane(__float_as_uint(v), l));
}
__device__ __forceinline__ unsigned rlu(unsigned v, int l) {
    return (unsigned)__builtin_amdgcn_readlane((int)v, l);
}
__device__ __forceinline__ float fd2(unsigned wp, unsigned vp, float acc) {
    return __builtin_amdgcn_fdot2(__builtin_bit_cast(hh2, wp),
                                  __builtin_bit_cast(hh2, vp), acc, false);
}
__device__ __forceinline__ unsigned alignb(unsigned hi, unsigned lo) {
    return __builtin_amdgcn_alignbit(hi, lo, 16);
}
__device__ __forceinline__ float fast_tanh(float v) {
    float e = __expf(2.0f * v);
    return 1.0f - 2.0f / (e + 1.0f);
}
// Opaque-launder: forces the value into a resident VGPR and hides its
// provenance so readlane(v, const) cannot be folded back into a uniform
// scalar load (which would re-create the R4 SMEM-serialization failure).
__device__ __forceinline__ unsigned opq(unsigned v) { asm volatile("" : "+v"(v)); return v; }
__device__ __forceinline__ float opqf(float v)      { asm volatile("" : "+v"(v)); return v; }

// Packed-weight table layout (u32 indices):
//  C2P @0    (192): idx=jp*50+(o*5+i), jp<3 : (w2[e], w2[e+1]|0), e=(o*5+i)*5+2jp
//  C3P @192  (448): idx=jp*100+(o*10+i), jp<4: (w3[e], w3[e+1]|0), e=oi*7+2jp
//  D1P @640  (320): idx=jp*100+oi, jp<3
//  D2P @960  (320)
//  CDP @1280 (192): idx=p*32+k, p<5 : (code[2p][k], code[2p+1][k])
//  CKP @1472 (192): idx=c*16+kp    : (code[c][2kp], code[c][2kp+1])
//  CC2 @1664 (64) : f32 bits of (4 - sum_c code[c][k]^2)
__global__ __launch_bounds__(256) void pack_w_kernel(
    const float* __restrict__ w2, const float* __restrict__ w3,
    const float* __restrict__ d1w, const float* __restrict__ d2w,
    const float* __restrict__ code, unsigned* __restrict__ wpk)
{
    const int i = blockIdx.x * 256 + threadIdx.x;
    if (i >= 1728) return;
    unsigned outv = 0;
    if (i < 192) {
        if (i < 150) { int jp = i / 50, oi = i % 50, e = oi * 5 + 2 * jp;
            hh2 v; v[0] = (_Float16)w2[e]; v[1] = (_Float16)((jp < 2) ? w2[e + 1] : 0.f);
            outv = __builtin_bit_cast(unsigned, v); }
    } else if (i < 640) {
        int idx = i - 192;
        if (idx < 400) { int jp = idx / 100, oi = idx % 100, e = oi * 7 + 2 * jp;
            hh2 v; v[0] = (_Float16)w3[e]; v[1] = (_Float16)((jp < 3) ? w3[e + 1] : 0.f);
            outv = __builtin_bit_cast(unsigned, v); }
    } else if (i < 960) {
        int idx = i - 640;
        if (idx < 300) { int jp = idx / 100, oi = idx % 100, e = oi * 5 + 2 * jp;
            hh2 v; v[0] = (_Float16)d1w[e]; v[1] = (_Float16)((jp < 2) ? d1w[e + 1] : 0.f);
            outv = __builtin_bit_cast(unsigned, v); }
    } else if (i < 1280) {
        int idx = i - 960;
        if (idx < 300) { int jp = idx / 100, oi = idx % 100, e = oi * 5 + 2 * jp;
            hh2 v; v[0] = (_Float16)d2w[e]; v[1] = (_Float16)((jp < 2) ? d2w[e + 1] : 0.f);
            outv = __builtin_bit_cast(unsigned, v); }
    } else if (i < 1472) {
        int idx = i - 1280;
        if (idx < 160) { int p = idx / 32, k = idx % 32;
            hh2 v; v[0] = (_Float16)code[(2 * p) * 32 + k];
            v[1] = (_Float16)code[(2 * p + 1) * 32 + k];
            outv = __builtin_bit_cast(unsigned, v); }
    } else if (i < 1664) {
        int idx = i - 1472;
        if (idx < 160) { int c = idx / 16, kp = idx % 16;
            hh2 v; v[0] = (_Float16)code[c * 32 + 2 * kp];
            v[1] = (_Float16)code[c * 32 + 2 * kp + 1];
            outv = __builtin_bit_cast(unsigned, v); }
    } else {
        int k = i - 1664;
        if (k < 32) { float s = 0.f;
            for (int c = 0; c < 10; ++c) { float v = code[c * 32 + k]; s = fmaf(v, v, s); }
            outv = __float_as_uint(4.0f - s); }
    }
    wpk[i] = outv;
}

// ---------------------------------------------------------------------------
// fcw (512x5120 f32) -> f16
__global__ __launch_bounds__(256) void convert_w_kernel(
    const float* __restrict__ src, _Float16* __restrict__ dst)
{
    int i = blockIdx.x * 256 + threadIdx.x;
    float4 a = ((const float4*)src)[i * 2];
    float4 b = ((const float4*)src)[i * 2 + 1];
    h8 v;
    v[0] = (_Float16)a.x; v[1] = (_Float16)a.y; v[2] = (_Float16)a.z; v[3] = (_Float16)a.w;
    v[4] = (_Float16)b.x; v[5] = (_Float16)b.y; v[6] = (_Float16)b.z; v[7] = (_Float16)b.w;
    *(h8*)&dst[(size_t)i * 8] = v;
}

// ---------------------------------------------------------------------------
// One block per batch row, t0=2*tid, t1=t0+1. Conv/VQ via v_dot2_f32_f16 with
// pre-packed f16 weight pairs held in laundered VGPRs, broadcast by
// v_readlane (compile-time lane index); f32 accumulation.
__global__ __launch_bounds__(256, 4) void enc_dec_kernel(
    const float* __restrict__ x,
    const float* __restrict__ w1, const float* __restrict__ b1,
    const float* __restrict__ b2, const float* __restrict__ b3,
    const float* __restrict__ d1b, const float* __restrict__ d2b,
    const unsigned* __restrict__ wpk,
    _Float16* __restrict__ flat)
{
    __shared__ float xbuf[XS];
    __shared__ _Float16 bufA[NCH * TS];
    __shared__ _Float16 bufB[NCH * TS];

    const int tid  = threadIdx.x;
    const int lane = tid & 63;
    const int b    = blockIdx.x;
    const int t0   = tid * 2;          // even

    // ---- preload packed weights into per-lane VGPRs (opaque-laundered) ----
    unsigned wc2[3], wc3[7], wd1[5], wd2[5], wcd[3], wck[3];
    #pragma unroll
    for (int r = 0; r < 3; ++r) wc2[r] = opq(wpk[r * 64 + lane]);
    #pragma unroll
    for (int r = 0; r < 7; ++r) wc3[r] = opq(wpk[192 + r * 64 + lane]);
    #pragma unroll
    for (int r = 0; r < 5; ++r) wd1[r] = opq(wpk[640 + r * 64 + lane]);
    #pragma unroll
    for (int r = 0; r < 5; ++r) wd2[r] = opq(wpk[960 + r * 64 + lane]);
    #pragma unroll
    for (int r = 0; r < 3; ++r) wcd[r] = opq(wpk[1280 + r * 64 + lane]);
    #pragma unroll
    for (int r = 0; r < 3; ++r) wck[r] = opq(wpk[1472 + r * 64 + lane]);
    float cc2r = opqf(__uint_as_float(wpk[1664 + lane]));   // 4 - c2[k]
    float w1r = opqf(w1[min(lane, 14)]);
    float b1r = opqf((lane < 5)  ? b1[lane]  : 0.f);
    float bb2 = opqf((lane < 10) ? b2[lane]  : 0.f);
    float bb3 = opqf((lane < 10) ? b3[lane]  : 0.f);
    float bd1 = opqf((lane < 10) ? d1b[lane] : 0.f);
    float bd2 = opqf((lane < 10) ? d2b[lane] : 0.f);

    // ---- init: zero halos, load x row ----
    if (tid < 160) {
        int c = tid >> 4, j = tid & 15;
        int pos = c * TS + ((j < 8) ? j : TT + j);
        bufA[pos] = (_Float16)0.f;
        bufB[pos] = (_Float16)0.f;
    }
    if (tid < 8) xbuf[(tid < 4) ? tid : TT + tid] = 0.f;
    if (tid < 128)
        *(float4*)&xbuf[XH + tid * 4] = ((const float4*)(x + (size_t)b * TT))[tid];
    __syncthreads();

    // ================= conv1: 1ch -> 5ch, k=3, pad=1, relu =================
    {
        float xm = xbuf[XH + t0 - 1];
        float x0 = xbuf[XH + t0];
        float x1 = xbuf[XH + t0 + 1];
        float x2 = xbuf[XH + t0 + 2];
        #pragma unroll
        for (int o = 0; o < 5; ++o) {
            float k0 = rlf(w1r, o * 3 + 0);
            float k1 = rlf(w1r, o * 3 + 1);
            float k2 = rlf(w1r, o * 3 + 2);
            float bb = rlf(b1r, o);
            float a0 = fmaf(k0, xm, fmaf(k1, x0, fmaf(k2, x1, bb)));
            float a1 = fmaf(k0, x0, fmaf(k1, x1, fmaf(k2, x2, bb)));
            hh2 st; st[0] = (_Float16)fmaxf(a0, 0.f); st[1] = (_Float16)fmaxf(a1, 0.f);
            *(hh2*)&bufA[o * TS + HO + t0] = st;
        }
    }
    __syncthreads();

    // ================= conv2: 5ch -> 10ch, k=5, pad=2, relu ================
    {
        float a0[10], a1[10];
        #pragma unroll
        for (int o = 0; o < 10; ++o) { float bb = rlf(bb2, o); a0[o] = bb; a1[o] = bb; }
        #pragma unroll
        for (int i = 0; i < 5; ++i) {
            const _Float16* row = &bufA[i * TS + HO + t0];
            unsigned Pm2 = *(const unsigned*)(row - 2);
            unsigned P0  = *(const unsigned*)(row);
            unsigned P2  = *(const unsigned*)(row + 2);
            unsigned Sm1 = alignb(P0, Pm2);     // (v-1, v0)
            unsigned S1  = alignb(P2, P0);      // (v1, v2)
            unsigned S3  = alignb(P2, P2);      // (v3, v2)
            #pragma unroll
            for (int o = 0; o < 10; ++o) {
                const int oi = o * 5 + i;
                unsigned q0 = rlu(wc2[(oi      ) >> 6], (oi      ) & 63);
                unsigned q1 = rlu(wc2[(oi +  50) >> 6], (oi +  50) & 63);
                unsigned q2 = rlu(wc2[(oi + 100) >> 6], (oi + 100) & 63);
                a0[o] = fd2(q0, Pm2, a0[o]); a0[o] = fd2(q1, P0, a0[o]); a0[o] = fd2(q2, P2, a0[o]);
                a1[o] = fd2(q0, Sm1, a1[o]); a1[o] = fd2(q1, S1, a1[o]); a1[o] = fd2(q2, S3, a1[o]);
            }
        }
        #pragma unroll
        for (int o = 0; o < 10; ++o) {
            hh2 st; st[0] = (_Float16)fmaxf(a0[o], 0.f); st[1] = (_Float16)fmaxf(a1[o], 0.f);
            *(hh2*)&bufB[o * TS + HO + t0] = st;
        }
    }
    __syncthreads();

    // ================ conv3: 10ch -> 10ch, k=7, pad=3, tanh ================
    {
        float a0[10], a1[10];
        #pragma unroll
        for (int o = 0; o < 10; ++o) { float bb = rlf(bb3, o); a0[o] = bb; a1[o] = bb; }
        #pragma unroll
        for (int i = 0; i < 10; ++i) {
            const _Float16* row = &bufB[i * TS + HO + t0];
            unsigned Pm4 = *(const unsigned*)(row - 4);
            unsigned Pm2 = *(const unsigned*)(row - 2);
            unsigned P0  = *(const unsigned*)(row);
            unsigned P2  = *(const unsigned*)(row + 2);
            unsigned P4  = *(const unsigned*)(row + 4);
            unsigned Sm3 = alignb(Pm2, Pm4);
            unsigned Sm1 = alignb(P0, Pm2);
            unsigned S1  = alignb(P2, P0);
            unsigned S3  = alignb(P4, P2);
            #pragma unroll
            for (int o = 0; o < 10; ++o) {
                const int oi = o * 10 + i;
                unsigned q0 = rlu(wc3[(oi      ) >> 6], (oi      ) & 63);
                unsigned q1 = rlu(wc3[(oi + 100) >> 6], (oi + 100) & 63);
                unsigned q2 = rlu(wc3[(oi + 200) >> 6], (oi + 200) & 63);
                unsigned q3 = rlu(wc3[(oi + 300) >> 6], (oi + 300) & 63);
                a0[o] = fd2(q0, Sm3, a0[o]); a0[o] = fd2(q1, Sm1, a0[o]);
                a0[o] = fd2(q2, S1,  a0[o]); a0[o] = fd2(q3, S3,  a0[o]);
                a1[o] = fd2(q0, Pm2, a1[o]); a1[o] = fd2(q1, P0,  a1[o]);
                a1[o] = fd2(q2, P2,  a1[o]); a1[o] = fd2(q3, P4,  a1[o]);
            }
        }
        #pragma unroll
        for (int o = 0; o < 10; ++o) {
            hh2 st; st[0] = (_Float16)fast_tanh(a0[o]); st[1] = (_Float16)fast_tanh(a1[o]);
            *(hh2*)&bufA[o * TS + HO + t0] = st;
        }
    }
    __syncthreads();

    // ====== VQ: softmax(2*cross - c2 + 4) over 32 codes (shift-invariant) =====
    {
        unsigned hp0[5], hp1[5];
        #pragma unroll
        for (int p = 0; p < 5; ++p) {
            unsigned A = *(const unsigned*)&bufA[(2 * p)     * TS + HO + t0];
            unsigned B = *(const unsigned*)&bufA[(2 * p + 1) * TS + HO + t0];
            hp0[p] = __builtin_amdgcn_perm(B, A, 0x05040100);  // (h[2p](t0), h[2p+1](t0))
            hp1[p] = __builtin_amdgcn_perm(B, A, 0x07060302);  // (h[2p](t1), h[2p+1](t1))
        }
        float qv0[10] = {}, qv1[10] = {};
        float sum0 = 0.f, sum1 = 0.f;
        #pragma unroll
        for (int kp = 0; kp < 16; ++kp) {
            float e0a, e0b, e1a, e1b;
            #pragma unroll
            for (int h = 0; h < 2; ++h) {
                const int k = 2 * kp + h;
                float cr0 = 0.f, cr1 = 0.f;
                #pragma unroll
                for (int p = 0; p < 5; ++p) {
                    const int e = p * 32 + k;
                    unsigned cp = rlu(wcd[e >> 6], e & 63);
                    cr0 = fd2(cp, hp0[p], cr0);
                    cr1 = fd2(cp, hp1[p], cr1);
                }
                float sc = rlf(cc2r, k);
                float v0 = __expf(fmaf(2.f, cr0, sc));
                float v1 = __expf(fmaf(2.f, cr1, sc));
                sum0 += v0; sum1 += v1;
                if (h == 0) { e0a = v0; e1a = v1; } else { e0b = v0; e1b = v1; }
            }
            unsigned ep0 = __builtin_bit_cast(unsigned, __builtin_amdgcn_cvt_pkrtz(e0a, e0b));
            unsigned ep1 = __builtin_bit_cast(unsigned, __builtin_amdgcn_cvt_pkrtz(e1a, e1b));
            #pragma unroll
            for (int c = 0; c < 10; ++c) {
                const int e = c * 16 + kp;
                unsigned ck = rlu(wck[e >> 6], e & 63);
                qv0[c] = fd2(ck, ep0, qv0[c]);
                qv1[c] = fd2(ck, ep1, qv1[c]);
            }
        }
        float inv0 = 1.0f / sum0, inv1 = 1.0f / sum1;
        #pragma unroll
        for (int c = 0; c < 10; ++c) {
            hh2 st; st[0] = (_Float16)(qv0[c] * inv0); st[1] = (_Float16)(qv1[c] * inv1);
            *(hh2*)&bufB[c * TS + HO + t0] = st;
        }
    }
    __syncthreads();

    // ================= d1: 10ch -> 10ch, k=5, pad=2, relu ==================
    {
        float a0[10], a1[10];
        #pragma unroll
        for (int o = 0; o < 10; ++o) { float bb = rlf(bd1, o); a0[o] = bb; a1[o] = bb; }
        #pragma unroll
        for (int i = 0; i < 10; ++i) {
            const _Float16* row = &bufB[i * TS + HO + t0];
            unsigned Pm2 = *(const unsigned*)(row - 2);
            unsigned P0  = *(const unsigned*)(row);
            unsigned P2  = *(const unsigned*)(row + 2);
            unsigned Sm1 = alignb(P0, Pm2);
            unsigned S1  = alignb(P2, P0);
            unsigned S3  = alignb(P2, P2);
            #pragma unroll
            for (int o = 0; o < 10; ++o) {
                const int oi = o * 10 + i;
                unsigned q0 = rlu(wd1[(oi      ) >> 6], (oi      ) & 63);
                unsigned q1 = rlu(wd1[(oi + 100) >> 6], (oi + 100) & 63);
                unsigned q2 = rlu(wd1[(oi + 200) >> 6], (oi + 200) & 63);
                a0[o] = fd2(q0, Pm2, a0[o]); a0[o] = fd2(q1, P0, a0[o]); a0[o] = fd2(q2, P2, a0[o]);
                a1[o] = fd2(q0, Sm1, a1[o]); a1[o] = fd2(q1, S1, a1[o]); a1[o] = fd2(q2, S3, a1[o]);
            }
        }
        #pragma unroll
        for (int o = 0; o < 10; ++o) {
            hh2 st; st[0] = (_Float16)fmaxf(a0[o], 0.f); st[1] = (_Float16)fmaxf(a1[o], 0.f);
            *(hh2*)&bufA[o * TS + HO + t0] = st;
        }
    }
    __syncthreads();

    // ================= d2: 10ch -> 10ch, k=5, pad=2, relu ==================
    {
        float a0[10], a1[10];
        #pragma unroll
        for (int o = 0; o < 10; ++o) { float bb = rlf(bd2, o); a0[o] = bb; a1[o] = bb; }
        #pragma unroll
        for (int i = 0; i < 10; ++i) {
            const _Float16* row = &bufA[i * TS + HO + t0];
            unsigned Pm2 = *(const unsigned*)(row - 2);
            unsigned P0  = *(const unsigned*)(row);
            unsigned P2  = *(const unsigned*)(row + 2);
            unsigned Sm1 = alignb(P0, Pm2);
            unsigned S1  = alignb(P2, P0);
            unsigned S3  = alignb(P2, P2);
            #pragma unroll
            for (int o = 0; o < 10; ++o) {
                const int oi = o * 10 + i;
                unsigned q0 = rlu(wd2[(oi      ) >> 6], (oi      ) & 63);
                unsigned q1 = rlu(wd2[(oi + 100) >> 6], (oi + 100) & 63);
                unsigned q2 = rlu(wd2[(oi + 200) >> 6], (oi + 200) & 63);
                a0[o] = fd2(q0, Pm2, a0[o]); a0[o] = fd2(q1, P0, a0[o]); a0[o] = fd2(q2, P2, a0[o]);
                a1[o] = fd2(q0, Sm1, a1[o]); a1[o] = fd2(q1, S1, a1[o]); a1[o] = fd2(q2, S3, a1[o]);
            }
        }
        #pragma unroll
        for (int o = 0; o < 10; ++o) {
            hh2 st; st[0] = (_Float16)fmaxf(a0[o], 0.f); st[1] = (_Float16)fmaxf(a1[o], 0.f);
            *(hh2*)&bufB[o * TS + HO + t0] = st;
        }
    }
    __syncthreads();

    // ---- flat row: pure f16 16B copy ----
    {
        _Float16* dst = flat + (size_t)b * (NCH * TT);
        for (int i = tid; i < 640; i += 256) {
            int c  = i >> 6;
            int t8 = (i & 63) << 3;
            *(h8*)&dst[c * TT + t8] = *(const h8*)&bufB[c * TS + HO + t8];
        }
    }
}

// ---------------------------------------------------------------------------
// FC via f16 MFMA (unchanged).
__global__ __launch_bounds__(256, 1) void fc_mfma_kernel(
    const _Float16* __restrict__ A,
    const _Float16* __restrict__ W,
    const float* __restrict__ bias,
    float* __restrict__ out)
{
    __shared__ __align__(16) unsigned char smem[65536];

    const int tid  = threadIdx.x;
    const int lane = tid & 63;
    const int w    = tid >> 6;

    const int bid = blockIdx.x;
    const int swz = (bid & 7) * 16 + (bid >> 3);
    const int m0 = (swz >> 3) * 64;
    const int n0 = (swz & 7) * 64;

    const int l31 = lane & 31;
    const int lh  = lane >> 5;
    const int rl16 = lane >> 4;
    const int c_lds = lane & 15;

    f32x16 acc00 = {}, acc01 = {}, acc10 = {}, acc11 = {};

    const _Float16* Asrc = A + (size_t)m0 * K_FC;
    const _Float16* Wsrc = W + (size_t)n0 * K_FC;

    auto stage = [&](int buf, int s) {
        unsigned char* Ad = smem + buf * 32768;
        unsigned char* Bd = Ad + 16384;
        const int k0 = s * 128;
        #pragma unroll
        for (int j = 0; j < 4; ++j) {
            const int i = w * 4 + j;
            const int rloc = 4 * i + rl16;
            const int csrc = c_lds ^ (rloc & 7);
            __builtin_amdgcn_global_load_lds(
                (GAS*)(Asrc + (size_t)rloc * K_FC + k0 + csrc * 8),
                (LAS*)(Ad + i * 1024), 16, 0, 0);
        }
        #pragma unroll
        for (int j = 0; j < 4; ++j) {
            const int i = w * 4 + j;
            const int rloc = 4 * i + rl16;
            const int csrc = c_lds ^ (rloc & 7);
            __builtin_amdgcn_global_load_lds(
                (GAS*)(Wsrc + (size_t)rloc * K_FC + k0 + csrc * 8),
                (LAS*)(Bd + i * 1024), 16, 0, 0);
        }
    };

    stage(0, 0);
    __syncthreads();

    for (int s = 0; s < 40; ++s) {
        const int cur = s & 1;
        if (s + 1 < 40) stage(cur ^ 1, s + 1);

        const unsigned char* Ab = smem + cur * 32768;
        const unsigned char* Bb = Ab + 16384;
        #pragma unroll
        for (int ks = 0; ks < 2; ++ks) {
            const int chunk = w * 4 + ks * 2 + lh;
            const int swzo  = ((chunk ^ (lane & 7)) << 4);
            h8 af0 = *(const h8*)(Ab +        l31 * 256 + swzo);
            h8 af1 = *(const h8*)(Ab + 8192 + l31 * 256 + swzo);
            h8 bf0 = *(const h8*)(Bb +        l31 * 256 + swzo);
            h8 bf1 = *(const h8*)(Bb + 8192 + l31 * 256 + swzo);
            acc00 = __builtin_amdgcn_mfma_f32_32x32x16_f16(af0, bf0, acc00, 0, 0, 0);
            acc01 = __builtin_amdgcn_mfma_f32_32x32x16_f16(af0, bf1, acc01, 0, 0, 0);
            acc10 = __builtin_amdgcn_mfma_f32_32x32x16_f16(af1, bf0, acc10, 0, 0, 0);
            acc11 = __builtin_amdgcn_mfma_f32_32x32x16_f16(af1, bf1, acc11, 0, 0, 0);
        }
        __syncthreads();
    }

    float* red = (float*)smem;
    {
        float* base = red + w * 4096;
        #pragma unroll
        for (int rq = 0; rq < 4; ++rq) {
            float4 v;
            v.x = acc00[rq*4+0]; v.y = acc00[rq*4+1]; v.z = acc00[rq*4+2]; v.w = acc00[rq*4+3];
            *(float4*)&base[0 * 1024 + rq * 256 + lane * 4] = v;
            v.x = acc01[rq*4+0]; v.y = acc01[rq*4+1]; v.z = acc01[rq*4+2]; v.w = acc01[rq*4+3];
            *(float4*)&base[1 * 1024 + rq * 256 + lane * 4] = v;
            v.x = acc10[rq*4+0]; v.y = acc10[rq*4+1]; v.z = acc10[rq*4+2]; v.w = acc10[rq*4+3];
            *(float4*)&base[2 * 1024 + rq * 256 + lane * 4] = v;
            v.x = acc11[rq*4+0]; v.y = acc11[rq*4+1]; v.z = acc11[rq*4+2]; v.w = acc11[rq*4+3];
            *(float4*)&base[3 * 1024 + rq * 256 + lane * 4] = v;
        }
    }
    __syncthreads();
    {
        const int f  = tid >> 6;
        const int lo = tid & 63;
        const int mf = f >> 1, nf = f & 1;
        const int n  = nf * 32 + (lo & 31);
        const float bv = bias[n0 + n];
        #pragma unroll
        for (int rq = 0; rq < 4; ++rq) {
            const int idx = f * 1024 + rq * 256 + lo * 4;
            float4 s0 = *(const float4*)&red[idx];
            float4 s1 = *(const float4*)&red[4096 + idx];
            float4 s2 = *(const float4*)&red[8192 + idx];
            float4 s3 = *(const float4*)&red[12288 + idx];
            #pragma unroll
            for (int rr = 0; rr < 4; ++rr) {
                float sum = ((const float*)&s0)[rr] + ((const float*)&s1)[rr]
                          + ((const float*)&s2)[rr] + ((const float*)&s3)[rr];
                const int m = mf * 32 + rr + 8 * rq + 4 * (lo >> 5);
                out[(size_t)(m0 + m) * 512 + n0 + n] = fast_tanh(sum + bv);
            }
        }
    }
}

extern "C" void kernel_launch(void* const* d_in, const int* in_sizes, int n_in,
                              void* d_out, int out_size, void* d_ws, size_t ws_size,
                              hipStream_t stream) {
    const float* x    = (const float*)d_in[0];
    const float* w1   = (const float*)d_in[1];
    const float* b1   = (const float*)d_in[2];
    const float* w2   = (const float*)d_in[3];
    const float* b2   = (const float*)d_in[4];
    const float* w3   = (const float*)d_in[5];
    const float* b3   = (const float*)d_in[6];
    const float* code = (const float*)d_in[7];
    const float* d1w  = (const float*)d_in[8];
    const float* d1b  = (const float*)d_in[9];
    const float* d2w  = (const float*)d_in[10];
    const float* d2b  = (const float*)d_in[11];
    const float* fcw  = (const float*)d_in[12];
    const float* fcb  = (const float*)d_in[13];
    float* out = (float*)d_out;

    _Float16* flat_h = (_Float16*)d_ws;                          // 10.0 MB
    _Float16* fcw_h  = (_Float16*)((char*)d_ws + 10485760);      //  5.0 MB
    unsigned* wpk    = (unsigned*)((char*)d_ws + 15728640);      //  ~7 KB

    const int Bsz = in_sizes[0] / TT;   // 1024

    pack_w_kernel<<<7, 256, 0, stream>>>(w2, w3, d1w, d2w, code, wpk);
    convert_w_kernel<<<1280, 256, 0, stream>>>(fcw, fcw_h);
    enc_dec_kernel<<<Bsz, 256, 0, stream>>>(x, w1, b1, b2, b3, d1b, d2b, wpk, flat_h);
    fc_mfma_kernel<<<128, 256, 0, stream>>>(flat_h, fcw_h, fcb, out);
}

// Round 8
// 70.798 us; speedup vs baseline: 1.3351x; 1.3351x over previous
//
#include <hip/hip_runtime.h>
#include <hip/hip_bf16.h>

#define TT 512
#define XS 520      // xbuf (f32): 4-halo | 512 | 4-halo
#define XH 4
#define RS 16       // activation row: 16 f16 ch-slots (32 B)
#define RH 8        // row halo (t=-8..519 -> rows 0..527)
#define NROW 528
#define K_FC 5120

typedef _Float16 hh2 __attribute__((ext_vector_type(2)));
typedef _Float16 h8 __attribute__((ext_vector_type(8)));
typedef float f32x16 __attribute__((ext_vector_type(16)));
typedef __attribute__((address_space(1))) const void GAS;
typedef __attribute__((address_space(3))) void LAS;

__device__ __forceinline__ float fast_tanh(float v) {
    float e = __expf(2.0f * v);
    return 1.0f - 2.0f / (e + 1.0f);
}
__device__ __forceinline__ unsigned pk(float a, float b) {
    return __builtin_bit_cast(unsigned, __builtin_amdgcn_cvt_pkrtz(a, b));
}

// ---------------------------------------------------------------------------
// Weight table in MFMA A-fragment layout (32x32x16 f16):
// lane l: row = l&31, k = (l>>5)*8 + e.  One uint4 (=h8) entry per (j, lane).
//  conv2 @0    : 5 j  (A[o][k]=w2[(o*5+k)*5+j],  o<10, k<5)
//  conv3 @320  : 7 j  (w3[(o*10+k)*7+j], k<10)
//  d1    @768  : 5 j  (d1w[(o*10+k)*5+j])
//  d2    @1088 : 5 j  (d2w[(o*10+k)*5+j])
//  cross @1408 : 1    (A[kc][ch] = 2*code[ch*32+kc], ch<10; kc=l&31 all 32)
//  q     @1472 : 2 ks (A[o][code] = code[o*32 + ks*16 + k], o<10)
//  c2tab       : 32 f32 bits of (4 - sum_c code[c][k]^2)
__global__ __launch_bounds__(256) void pack_w_kernel(
    const float* __restrict__ w2, const float* __restrict__ w3,
    const float* __restrict__ d1w, const float* __restrict__ d2w,
    const float* __restrict__ code, uint4* __restrict__ wtab,
    unsigned* __restrict__ c2tab)
{
    const int i = blockIdx.x * 256 + threadIdx.x;
    if (i < 1600) {
        const int lane = i & 63;
        const int o = lane & 31;
        const int hi = lane >> 5;
        h8 v = {};
        if (i < 320) {                       // conv2
            const int j = i >> 6;
            #pragma unroll
            for (int e = 0; e < 8; ++e) {
                int k = hi * 8 + e;
                if (o < 10 && k < 5) v[e] = (_Float16)w2[(o * 5 + k) * 5 + j];
            }
        } else if (i < 768) {                // conv3
            const int j = (i - 320) >> 6;
            #pragma unroll
            for (int e = 0; e < 8; ++e) {
                int k = hi * 8 + e;
                if (o < 10 && k < 10) v[e] = (_Float16)w3[(o * 10 + k) * 7 + j];
            }
        } else if (i < 1088) {               // d1
            const int j = (i - 768) >> 6;
            #pragma unroll
            for (int e = 0; e < 8; ++e) {
                int k = hi * 8 + e;
                if (o < 10 && k < 10) v[e] = (_Float16)d1w[(o * 10 + k) * 5 + j];
            }
        } else if (i < 1408) {               // d2
            const int j = (i - 1088) >> 6;
            #pragma unroll
            for (int e = 0; e < 8; ++e) {
                int k = hi * 8 + e;
                if (o < 10 && k < 10) v[e] = (_Float16)d2w[(o * 10 + k) * 5 + j];
            }
        } else if (i < 1472) {               // cross (rows = all 32 codes)
            #pragma unroll
            for (int e = 0; e < 8; ++e) {
                int ch = hi * 8 + e;
                if (ch < 10) v[e] = (_Float16)(2.0f * code[ch * 32 + o]);
            }
        } else {                             // q, 2 k-steps
            const int ks = (i - 1472) >> 6;
            #pragma unroll
            for (int e = 0; e < 8; ++e) {
                int kc = ks * 16 + hi * 8 + e;
                if (o < 10) v[e] = (_Float16)code[o * 32 + kc];
            }
        }
        wtab[i] = __builtin_bit_cast(uint4, v);
    } else if (i < 1632) {
        int k = i - 1600;
        float s = 0.f;
        for (int c = 0; c < 10; ++c) { float cv = code[c * 32 + k]; s = fmaf(cv, cv, s); }
        c2tab[k] = __float_as_uint(4.0f - s);
    }
}

// ---------------------------------------------------------------------------
// fcw (512x5120 f32) -> f16
__global__ __launch_bounds__(256) void convert_w_kernel(
    const float* __restrict__ src, _Float16* __restrict__ dst)
{
    int i = blockIdx.x * 256 + threadIdx.x;
    float4 a = ((const float4*)src)[i * 2];
    float4 b = ((const float4*)src)[i * 2 + 1];
    h8 v;
    v[0] = (_Float16)a.x; v[1] = (_Float16)a.y; v[2] = (_Float16)a.z; v[3] = (_Float16)a.w;
    v[4] = (_Float16)b.x; v[5] = (_Float16)b.y; v[6] = (_Float16)b.z; v[7] = (_Float16)b.w;
    *(h8*)&dst[(size_t)i * 8] = v;
}

// ---------------------------------------------------------------------------
// Generic conv stage: D[o][t] = act( bias[o] + sum_j sum_k W[o][k][j] S[k][t+j-P] )
// via J MFMAs per 32-t tile. acc C-layout: col=lane&31, row=(r&3)+8*(r>>2)+4*hi.
template<int J, int P, int ACT>   // ACT: 0 = relu, 1 = tanh
__device__ __forceinline__ void conv_stage(
    const _Float16* __restrict__ src, _Float16* __restrict__ dst,
    const uint4* __restrict__ wtab, int wbase, const float* __restrict__ sb)
{
    const int tid = threadIdx.x;
    const int lane = tid & 63;
    const int wv = tid >> 6;
    const int l31 = lane & 31;
    const int hi = lane >> 5;

    uint4 wf[J];
    #pragma unroll
    for (int j = 0; j < J; ++j) wf[j] = wtab[wbase + j * 64 + lane];
    float bias[6];
    #pragma unroll
    for (int r = 0; r < 6; ++r) bias[r] = sb[(r & 3) + 8 * (r >> 2) + 4 * hi];

    #pragma unroll
    for (int tile = 0; tile < 4; ++tile) {
        const int tcol = wv * 128 + tile * 32 + l31;
        f32x16 acc = {};
        #pragma unroll
        for (int j = 0; j < J; ++j) {
            h8 bf = *(const h8*)(src + (tcol + RH - P + j) * RS + hi * 8);
            acc = __builtin_amdgcn_mfma_f32_32x32x16_f16(
                __builtin_bit_cast(h8, wf[j]), bf, acc, 0, 0, 0);
        }
        float v[6];
        #pragma unroll
        for (int r = 0; r < 6; ++r) {
            float t = acc[r] + bias[r];
            v[r] = (ACT == 0) ? fmaxf(t, 0.f) : fast_tanh(t);
        }
        unsigned* drow = (unsigned*)(dst + (tcol + RH) * RS);
        drow[hi * 2 + 0] = pk(v[0], v[1]);   // ch (0,1)+4hi
        drow[hi * 2 + 1] = pk(v[2], v[3]);   // ch (2,3)+4hi
        if (!hi) drow[4] = pk(v[4], v[5]);   // ch 8,9
    }
}

// ---------------------------------------------------------------------------
// VQ: scores = 2*code^T h - c2 + 4 (1 MFMA), exp, denom via shfl_xor(32),
// q = code @ e (2 MFMAs, B-frag assembled in-register), scale by 1/denom.
__device__ __forceinline__ void vq_stage(
    const _Float16* __restrict__ src, _Float16* __restrict__ dst,
    const uint4* __restrict__ wtab, const float* __restrict__ sc2)
{
    const int tid = threadIdx.x;
    const int lane = tid & 63;
    const int wv = tid >> 6;
    const int l31 = lane & 31;
    const int hi = lane >> 5;

    const h8 wcr = __builtin_bit_cast(h8, wtab[1408 + lane]);
    const h8 wq0 = __builtin_bit_cast(h8, wtab[1472 + lane]);
    const h8 wq1 = __builtin_bit_cast(h8, wtab[1536 + lane]);
    float c2s[16];
    #pragma unroll
    for (int r = 0; r < 16; ++r) c2s[r] = sc2[(r & 3) + 8 * (r >> 2) + 4 * hi];

    #pragma unroll
    for (int tile = 0; tile < 4; ++tile) {
        const int tcol = wv * 128 + tile * 32 + l31;
        h8 bf = *(const h8*)(src + (tcol + RH) * RS + hi * 8);
        f32x16 sacc = {};
        sacc = __builtin_amdgcn_mfma_f32_32x32x16_f16(wcr, bf, sacc, 0, 0, 0);

        float e[16], sum = 0.f;
        #pragma unroll
        for (int r = 0; r < 16; ++r) { e[r] = __expf(sacc[r] + c2s[r]); sum += e[r]; }
        float denom = sum + __shfl_xor(sum, 32);
        float inv = 1.0f / denom;
        float so[16];
        #pragma unroll
        for (int r = 0; r < 16; ++r) so[r] = __shfl_xor(e[r], 32);

        // B-frag: lane holds e[code = hi*8+idx (+16*ks)] for its col.
        float s0[8], s1[8];
        #pragma unroll
        for (int q = 0; q < 4; ++q) {
            s0[q]     = hi ? so[4 + q]  : e[q];        // codes 0-3 / 8-11
            s0[4 + q] = hi ? e[4 + q]   : so[q];       // codes 4-7 / 12-15
            s1[q]     = hi ? so[12 + q] : e[8 + q];    // codes 16-19 / 24-27
            s1[4 + q] = hi ? e[12 + q]  : so[8 + q];   // codes 20-23 / 28-31
        }
        uint4 b0u, b1u;
        b0u.x = pk(s0[0], s0[1]); b0u.y = pk(s0[2], s0[3]);
        b0u.z = pk(s0[4], s0[5]); b0u.w = pk(s0[6], s0[7]);
        b1u.x = pk(s1[0], s1[1]); b1u.y = pk(s1[2], s1[3]);
        b1u.z = pk(s1[4], s1[5]); b1u.w = pk(s1[6], s1[7]);

        f32x16 qacc = {};
        qacc = __builtin_amdgcn_mfma_f32_32x32x16_f16(wq0, __builtin_bit_cast(h8, b0u), qacc, 0, 0, 0);
        qacc = __builtin_amdgcn_mfma_f32_32x32x16_f16(wq1, __builtin_bit_cast(h8, b1u), qacc, 0, 0, 0);

        float v[6];
        #pragma unroll
        for (int r = 0; r < 6; ++r) v[r] = qacc[r] * inv;
        unsigned* drow = (unsigned*)(dst + (tcol + RH) * RS);
        drow[hi * 2 + 0] = pk(v[0], v[1]);
        drow[hi * 2 + 1] = pk(v[2], v[3]);
        if (!hi) drow[4] = pk(v[4], v[5]);
    }
}

// ---------------------------------------------------------------------------
__global__ __launch_bounds__(256, 4) void enc_dec_kernel(
    const float* __restrict__ x,
    const float* __restrict__ w1, const float* __restrict__ b1,
    const float* __restrict__ b2, const float* __restrict__ b3,
    const float* __restrict__ d1b, const float* __restrict__ d2b,
    const uint4* __restrict__ wtab, const unsigned* __restrict__ c2tab,
    _Float16* __restrict__ flat)
{
    __shared__ float xbuf[XS];
    __shared__ _Float16 bufA[NROW * RS];
    __shared__ _Float16 bufB[NROW * RS];
    __shared__ float sc2[32];
    __shared__ float sbias[4][16];

    const int tid = threadIdx.x;
    const int b = blockIdx.x;

    // ---- init: zero both activation buffers (halos + pad cols must be 0) ----
    {
        uint4 z; z.x = 0; z.y = 0; z.z = 0; z.w = 0;
        uint4* pa = (uint4*)bufA;
        uint4* pb = (uint4*)bufB;
        for (int i = tid; i < NROW * RS / 8; i += 256) { pa[i] = z; pb[i] = z; }
    }
    if (tid < 8) xbuf[(tid < 4) ? tid : TT + tid] = 0.f;
    if (tid < 128)
        *(float4*)&xbuf[XH + tid * 4] = ((const float4*)(x + (size_t)b * TT))[tid];
    if (tid >= 128 && tid < 160) sc2[tid - 128] = __uint_as_float(c2tab[tid - 128]);
    if (tid >= 160 && tid < 224) {
        int s = (tid - 160) >> 4, i = (tid - 160) & 15;
        float v = 0.f;
        if (i < 10) v = (s == 0) ? b2[i] : (s == 1) ? b3[i] : (s == 2) ? d1b[i] : d2b[i];
        sbias[s][i] = v;
    }
    __syncthreads();

    // ---- conv1 (scalar, tiny): 1->5ch k=3 relu, write [t][16] rows ----
    {
        const int t0 = tid * 2;
        float xm = xbuf[XH + t0 - 1], x0v = xbuf[XH + t0];
        float x1v = xbuf[XH + t0 + 1], x2v = xbuf[XH + t0 + 2];
        h8 r0 = {}; h8 r1 = {};
        #pragma unroll
        for (int o = 0; o < 5; ++o) {
            float k0 = w1[o * 3], k1 = w1[o * 3 + 1], k2 = w1[o * 3 + 2], bb = b1[o];
            float a0 = fmaf(k0, xm,  fmaf(k1, x0v, fmaf(k2, x1v, bb)));
            float a1 = fmaf(k0, x0v, fmaf(k1, x1v, fmaf(k2, x2v, bb)));
            r0[o] = (_Float16)fmaxf(a0, 0.f);
            r1[o] = (_Float16)fmaxf(a1, 0.f);
        }
        *(h8*)&bufA[(t0 + RH) * RS] = r0;
        *(h8*)&bufA[(t0 + 1 + RH) * RS] = r1;
    }
    __syncthreads();

    conv_stage<5, 2, 0>(bufA, bufB, wtab, 0,    sbias[0]);   // conv2
    __syncthreads();
    conv_stage<7, 3, 1>(bufB, bufA, wtab, 320,  sbias[1]);   // conv3 (tanh)
    __syncthreads();
    vq_stage(bufA, bufB, wtab, sc2);                          // VQ
    __syncthreads();
    conv_stage<5, 2, 0>(bufB, bufA, wtab, 768,  sbias[2]);   // d1
    __syncthreads();
    conv_stage<5, 2, 0>(bufA, bufB, wtab, 1088, sbias[3]);   // d2
    __syncthreads();

    // ---- flat [c][t] from bufB [t][16] ----
    {
        _Float16* dst = flat + (size_t)b * (10 * TT);
        for (int i = tid; i < 640; i += 256) {
            int c = i >> 6, t8 = (i & 63) << 3;
            h8 v;
            #pragma unroll
            for (int r = 0; r < 8; ++r) v[r] = bufB[(t8 + r + RH) * RS + c];
            *(h8*)&dst[c * TT + t8] = v;
        }
    }
}

// ---------------------------------------------------------------------------
// FC via f16 MFMA (unchanged).
__global__ __launch_bounds__(256, 1) void fc_mfma_kernel(
    const _Float16* __restrict__ A,
    const _Float16* __restrict__ W,
    const float* __restrict__ bias,
    float* __restrict__ out)
{
    __shared__ __align__(16) unsigned char smem[65536];

    const int tid  = threadIdx.x;
    const int lane = tid & 63;
    const int w    = tid >> 6;

    const int bid = blockIdx.x;
    const int swz = (bid & 7) * 16 + (bid >> 3);
    const int m0 = (swz >> 3) * 64;
    const int n0 = (swz & 7) * 64;

    const int l31 = lane & 31;
    const int lh  = lane >> 5;
    const int rl16 = lane >> 4;
    const int c_lds = lane & 15;

    f32x16 acc00 = {}, acc01 = {}, acc10 = {}, acc11 = {};

    const _Float16* Asrc = A + (size_t)m0 * K_FC;
    const _Float16* Wsrc = W + (size_t)n0 * K_FC;

    auto stage = [&](int buf, int s) {
        unsigned char* Ad = smem + buf * 32768;
        unsigned char* Bd = Ad + 16384;
        const int k0 = s * 128;
        #pragma unroll
        for (int j = 0; j < 4; ++j) {
            const int i = w * 4 + j;
            const int rloc = 4 * i + rl16;
            const int csrc = c_lds ^ (rloc & 7);
            __builtin_amdgcn_global_load_lds(
                (GAS*)(Asrc + (size_t)rloc * K_FC + k0 + csrc * 8),
                (LAS*)(Ad + i * 1024), 16, 0, 0);
        }
        #pragma unroll
        for (int j = 0; j < 4; ++j) {
            const int i = w * 4 + j;
            const int rloc = 4 * i + rl16;
            const int csrc = c_lds ^ (rloc & 7);
            __builtin_amdgcn_global_load_lds(
                (GAS*)(Wsrc + (size_t)rloc * K_FC + k0 + csrc * 8),
                (LAS*)(Bd + i * 1024), 16, 0, 0);
        }
    };

    stage(0, 0);
    __syncthreads();

    for (int s = 0; s < 40; ++s) {
        const int cur = s & 1;
        if (s + 1 < 40) stage(cur ^ 1, s + 1);

        const unsigned char* Ab = smem + cur * 32768;
        const unsigned char* Bb = Ab + 16384;
        #pragma unroll
        for (int ks = 0; ks < 2; ++ks) {
            const int chunk = w * 4 + ks * 2 + lh;
            const int swzo  = ((chunk ^ (lane & 7)) << 4);
            h8 af0 = *(const h8*)(Ab +        l31 * 256 + swzo);
            h8 af1 = *(const h8*)(Ab + 8192 + l31 * 256 + swzo);
            h8 bf0 = *(const h8*)(Bb +        l31 * 256 + swzo);
            h8 bf1 = *(const h8*)(Bb + 8192 + l31 * 256 + swzo);
            acc00 = __builtin_amdgcn_mfma_f32_32x32x16_f16(af0, bf0, acc00, 0, 0, 0);
            acc01 = __builtin_amdgcn_mfma_f32_32x32x16_f16(af0, bf1, acc01, 0, 0, 0);
            acc10 = __builtin_amdgcn_mfma_f32_32x32x16_f16(af1, bf0, acc10, 0, 0, 0);
            acc11 = __builtin_amdgcn_mfma_f32_32x32x16_f16(af1, bf1, acc11, 0, 0, 0);
        }
        __syncthreads();
    }

    float* red = (float*)smem;
    {
        float* base = red + w * 4096;
        #pragma unroll
        for (int rq = 0; rq < 4; ++rq) {
            float4 v;
            v.x = acc00[rq*4+0]; v.y = acc00[rq*4+1]; v.z = acc00[rq*4+2]; v.w = acc00[rq*4+3];
            *(float4*)&base[0 * 1024 + rq * 256 + lane * 4] = v;
            v.x = acc01[rq*4+0]; v.y = acc01[rq*4+1]; v.z = acc01[rq*4+2]; v.w = acc01[rq*4+3];
            *(float4*)&base[1 * 1024 + rq * 256 + lane * 4] = v;
            v.x = acc10[rq*4+0]; v.y = acc10[rq*4+1]; v.z = acc10[rq*4+2]; v.w = acc10[rq*4+3];
            *(float4*)&base[2 * 1024 + rq * 256 + lane * 4] = v;
            v.x = acc11[rq*4+0]; v.y = acc11[rq*4+1]; v.z = acc11[rq*4+2]; v.w = acc11[rq*4+3];
            *(float4*)&base[3 * 1024 + rq * 256 + lane * 4] = v;
        }
    }
    __syncthreads();
    {
        const int f  = tid >> 6;
        const int lo = tid & 63;
        const int mf = f >> 1, nf = f & 1;
        const int n  = nf * 32 + (lo & 31);
        const float bv = bias[n0 + n];
        #pragma unroll
        for (int rq = 0; rq < 4; ++rq) {
            const int idx = f * 1024 + rq * 256 + lo * 4;
            float4 s0 = *(const float4*)&red[idx];
            float4 s1 = *(const float4*)&red[4096 + idx];
            float4 s2 = *(const float4*)&red[8192 + idx];
            float4 s3 = *(const float4*)&red[12288 + idx];
            #pragma unroll
            for (int rr = 0; rr < 4; ++rr) {
                float sum = ((const float*)&s0)[rr] + ((const float*)&s1)[rr]
                          + ((const float*)&s2)[rr] + ((const float*)&s3)[rr];
                const int m = mf * 32 + rr + 8 * rq + 4 * (lo >> 5);
                out[(size_t)(m0 + m) * 512 + n0 + n] = fast_tanh(sum + bv);
            }
        }
    }
}

extern "C" void kernel_launch(void* const* d_in, const int* in_sizes, int n_in,
                              void* d_out, int out_size, void* d_ws, size_t ws_size,
                              hipStream_t stream) {
    const float* x    = (const float*)d_in[0];
    const float* w1   = (const float*)d_in[1];
    const float* b1   = (const float*)d_in[2];
    const float* w2   = (const float*)d_in[3];
    const float* b2   = (const float*)d_in[4];
    const float* w3   = (const float*)d_in[5];
    const float* b3   = (const float*)d_in[6];
    const float* code = (const float*)d_in[7];
    const float* d1w  = (const float*)d_in[8];
    const float* d1b  = (const float*)d_in[9];
    const float* d2w  = (const float*)d_in[10];
    const float* d2b  = (const float*)d_in[11];
    const float* fcw  = (const float*)d_in[12];
    const float* fcb  = (const float*)d_in[13];
    float* out = (float*)d_out;

    _Float16* flat_h = (_Float16*)d_ws;                             // 10.0 MB
    _Float16* fcw_h  = (_Float16*)((char*)d_ws + 10485760);         //  5.0 MB
    uint4*    wtab   = (uint4*)((char*)d_ws + 15728640);            // 25.6 KB
    unsigned* c2tab  = (unsigned*)((char*)d_ws + 15728640 + 25600); // 128 B

    const int Bsz = in_sizes[0] / TT;   // 1024

    pack_w_kernel<<<7, 256, 0, stream>>>(w2, w3, d1w, d2w, code, wtab, c2tab);
    convert_w_kernel<<<1280, 256, 0, stream>>>(fcw, fcw_h);
    enc_dec_kernel<<<Bsz, 256, 0, stream>>>(x, w1, b1, b2, b3, d1b, d2b,
                                            wtab, c2tab, flat_h);
    fc_mfma_kernel<<<128, 256, 0, stream>>>(flat_h, fcw_h, fcb, out);
}

// Round 9
// 55.015 us; speedup vs baseline: 1.7181x; 1.2869x over previous
//
#include <hip/hip_runtime.h>
#include <hip/hip_bf16.h>

#define TT 512
#define XS 520      // xbuf (f32): 4-halo | 512 | 4-halo
#define XH 4
#define RS 16       // activation row: 16 f16 ch-slots (32 B)
#define RH 8        // row halo (t=-8..519 -> rows 0..527)
#define NROW 528
#define K_FC 5120

typedef _Float16 hh2 __attribute__((ext_vector_type(2)));
typedef _Float16 h8 __attribute__((ext_vector_type(8)));
typedef float f32x16 __attribute__((ext_vector_type(16)));
typedef __attribute__((address_space(1))) const void GAS;
typedef __attribute__((address_space(3))) void LAS;

__device__ __forceinline__ float fast_tanh(float v) {
    float e = __expf(2.0f * v);
    return 1.0f - 2.0f / (e + 1.0f);
}
__device__ __forceinline__ unsigned pk(float a, float b) {
    return __builtin_bit_cast(unsigned, __builtin_amdgcn_cvt_pkrtz(a, b));
}

// ---------------------------------------------------------------------------
// prep: blocks 0..1279 convert fcw f32->f16; blocks 1280..1286 pack the
// conv/VQ weight table in MFMA A-fragment layout (32x32x16 f16):
// lane l: row = l&31, k = (l>>5)*8 + e.
//  conv2 @0 (5j) | conv3 @320 (7j) | d1 @768 (5j) | d2 @1088 (5j)
//  cross @1408 (A[kc][ch]=2*code[ch][kc]) | q @1472 (2 ks)
//  c2tab: 32 f32 bits of (4 - sum_c code[c][k]^2)
__global__ __launch_bounds__(256) void prep_kernel(
    const float* __restrict__ fcw, _Float16* __restrict__ fcw_h,
    const float* __restrict__ w2, const float* __restrict__ w3,
    const float* __restrict__ d1w, const float* __restrict__ d2w,
    const float* __restrict__ code, uint4* __restrict__ wtab,
    unsigned* __restrict__ c2tab)
{
    if (blockIdx.x < 1280) {
        int i = blockIdx.x * 256 + threadIdx.x;
        float4 a = ((const float4*)fcw)[i * 2];
        float4 b = ((const float4*)fcw)[i * 2 + 1];
        h8 v;
        v[0] = (_Float16)a.x; v[1] = (_Float16)a.y; v[2] = (_Float16)a.z; v[3] = (_Float16)a.w;
        v[4] = (_Float16)b.x; v[5] = (_Float16)b.y; v[6] = (_Float16)b.z; v[7] = (_Float16)b.w;
        *(h8*)&fcw_h[(size_t)i * 8] = v;
        return;
    }
    const int i = (blockIdx.x - 1280) * 256 + threadIdx.x;
    if (i < 1600) {
        const int lane = i & 63;
        const int o = lane & 31;
        const int hi = lane >> 5;
        h8 v = {};
        if (i < 320) {                       // conv2
            const int j = i >> 6;
            #pragma unroll
            for (int e = 0; e < 8; ++e) {
                int k = hi * 8 + e;
                if (o < 10 && k < 5) v[e] = (_Float16)w2[(o * 5 + k) * 5 + j];
            }
        } else if (i < 768) {                // conv3
            const int j = (i - 320) >> 6;
            #pragma unroll
            for (int e = 0; e < 8; ++e) {
                int k = hi * 8 + e;
                if (o < 10 && k < 10) v[e] = (_Float16)w3[(o * 10 + k) * 7 + j];
            }
        } else if (i < 1088) {               // d1
            const int j = (i - 768) >> 6;
            #pragma unroll
            for (int e = 0; e < 8; ++e) {
                int k = hi * 8 + e;
                if (o < 10 && k < 10) v[e] = (_Float16)d1w[(o * 10 + k) * 5 + j];
            }
        } else if (i < 1408) {               // d2
            const int j = (i - 1088) >> 6;
            #pragma unroll
            for (int e = 0; e < 8; ++e) {
                int k = hi * 8 + e;
                if (o < 10 && k < 10) v[e] = (_Float16)d2w[(o * 10 + k) * 5 + j];
            }
        } else if (i < 1472) {               // cross
            #pragma unroll
            for (int e = 0; e < 8; ++e) {
                int ch = hi * 8 + e;
                if (ch < 10) v[e] = (_Float16)(2.0f * code[ch * 32 + o]);
            }
        } else {                             // q, 2 k-steps
            const int ks = (i - 1472) >> 6;
            #pragma unroll
            for (int e = 0; e < 8; ++e) {
                int kc = ks * 16 + hi * 8 + e;
                if (o < 10) v[e] = (_Float16)code[o * 32 + kc];
            }
        }
        wtab[i] = __builtin_bit_cast(uint4, v);
    } else if (i < 1632) {
        int k = i - 1600;
        float s = 0.f;
        for (int c = 0; c < 10; ++c) { float cv = code[c * 32 + k]; s = fmaf(cv, cv, s); }
        c2tab[k] = __float_as_uint(4.0f - s);
    }
}

// ---------------------------------------------------------------------------
// Conv stage via J MFMAs per 32-t tile; C-layout row=(r&3)+8*(r>>2)+4*hi.
template<int J, int P, int ACT>   // ACT: 0 = relu, 1 = tanh
__device__ __forceinline__ void conv_stage(
    const _Float16* __restrict__ src, _Float16* __restrict__ dst,
    const uint4* __restrict__ wtab, int wbase, const float* __restrict__ sb)
{
    const int tid = threadIdx.x;
    const int lane = tid & 63;
    const int wv = tid >> 6;
    const int l31 = lane & 31;
    const int hi = lane >> 5;

    uint4 wf[J];
    #pragma unroll
    for (int j = 0; j < J; ++j) wf[j] = wtab[wbase + j * 64 + lane];
    float bias[6];
    #pragma unroll
    for (int r = 0; r < 6; ++r) bias[r] = sb[(r & 3) + 8 * (r >> 2) + 4 * hi];

    #pragma unroll
    for (int tile = 0; tile < 4; ++tile) {
        const int tcol = wv * 128 + tile * 32 + l31;
        f32x16 acc = {};
        #pragma unroll
        for (int j = 0; j < J; ++j) {
            h8 bf = *(const h8*)(src + (tcol + RH - P + j) * RS + hi * 8);
            acc = __builtin_amdgcn_mfma_f32_32x32x16_f16(
                __builtin_bit_cast(h8, wf[j]), bf, acc, 0, 0, 0);
        }
        float v[6];
        #pragma unroll
        for (int r = 0; r < 6; ++r) {
            float t = acc[r] + bias[r];
            v[r] = (ACT == 0) ? fmaxf(t, 0.f) : fast_tanh(t);
        }
        unsigned* drow = (unsigned*)(dst + (tcol + RH) * RS);
        drow[hi * 2 + 0] = pk(v[0], v[1]);
        drow[hi * 2 + 1] = pk(v[2], v[3]);
        if (!hi) drow[4] = pk(v[4], v[5]);
    }
}

// Final conv stage: relu, store straight to flat[c*512 + t] in global.
template<int J, int P>
__device__ __forceinline__ void conv_stage_flat(
    const _Float16* __restrict__ src, _Float16* __restrict__ flatrow,
    const uint4* __restrict__ wtab, int wbase, const float* __restrict__ sb)
{
    const int tid = threadIdx.x;
    const int lane = tid & 63;
    const int wv = tid >> 6;
    const int l31 = lane & 31;
    const int hi = lane >> 5;

    uint4 wf[J];
    #pragma unroll
    for (int j = 0; j < J; ++j) wf[j] = wtab[wbase + j * 64 + lane];
    float bias[6];
    #pragma unroll
    for (int r = 0; r < 6; ++r) bias[r] = sb[(r & 3) + 8 * (r >> 2) + 4 * hi];

    #pragma unroll
    for (int tile = 0; tile < 4; ++tile) {
        const int tcol = wv * 128 + tile * 32 + l31;
        f32x16 acc = {};
        #pragma unroll
        for (int j = 0; j < J; ++j) {
            h8 bf = *(const h8*)(src + (tcol + RH - P + j) * RS + hi * 8);
            acc = __builtin_amdgcn_mfma_f32_32x32x16_f16(
                __builtin_bit_cast(h8, wf[j]), bf, acc, 0, 0, 0);
        }
        #pragma unroll
        for (int r = 0; r < 4; ++r)
            flatrow[(r + 4 * hi) * TT + tcol] = (_Float16)fmaxf(acc[r] + bias[r], 0.f);
        if (!hi) {
            flatrow[8 * TT + tcol] = (_Float16)fmaxf(acc[4] + bias[4], 0.f);
            flatrow[9 * TT + tcol] = (_Float16)fmaxf(acc[5] + bias[5], 0.f);
        }
    }
}

// ---------------------------------------------------------------------------
// VQ: scores via 1 MFMA, exp, denom via shfl_xor(32), q via 2 MFMAs.
__device__ __forceinline__ void vq_stage(
    const _Float16* __restrict__ src, _Float16* __restrict__ dst,
    const uint4* __restrict__ wtab, const float* __restrict__ sc2)
{
    const int tid = threadIdx.x;
    const int lane = tid & 63;
    const int wv = tid >> 6;
    const int l31 = lane & 31;
    const int hi = lane >> 5;

    const h8 wcr = __builtin_bit_cast(h8, wtab[1408 + lane]);
    const h8 wq0 = __builtin_bit_cast(h8, wtab[1472 + lane]);
    const h8 wq1 = __builtin_bit_cast(h8, wtab[1536 + lane]);
    float c2s[16];
    #pragma unroll
    for (int r = 0; r < 16; ++r) c2s[r] = sc2[(r & 3) + 8 * (r >> 2) + 4 * hi];

    #pragma unroll
    for (int tile = 0; tile < 4; ++tile) {
        const int tcol = wv * 128 + tile * 32 + l31;
        h8 bf = *(const h8*)(src + (tcol + RH) * RS + hi * 8);
        f32x16 sacc = {};
        sacc = __builtin_amdgcn_mfma_f32_32x32x16_f16(wcr, bf, sacc, 0, 0, 0);

        float e[16], sum = 0.f;
        #pragma unroll
        for (int r = 0; r < 16; ++r) { e[r] = __expf(sacc[r] + c2s[r]); sum += e[r]; }
        float denom = sum + __shfl_xor(sum, 32);
        float inv = 1.0f / denom;
        float so[16];
        #pragma unroll
        for (int r = 0; r < 16; ++r) so[r] = __shfl_xor(e[r], 32);

        float s0[8], s1[8];
        #pragma unroll
        for (int q = 0; q < 4; ++q) {
            s0[q]     = hi ? so[4 + q]  : e[q];
            s0[4 + q] = hi ? e[4 + q]   : so[q];
            s1[q]     = hi ? so[12 + q] : e[8 + q];
            s1[4 + q] = hi ? e[12 + q]  : so[8 + q];
        }
        uint4 b0u, b1u;
        b0u.x = pk(s0[0], s0[1]); b0u.y = pk(s0[2], s0[3]);
        b0u.z = pk(s0[4], s0[5]); b0u.w = pk(s0[6], s0[7]);
        b1u.x = pk(s1[0], s1[1]); b1u.y = pk(s1[2], s1[3]);
        b1u.z = pk(s1[4], s1[5]); b1u.w = pk(s1[6], s1[7]);

        f32x16 qacc = {};
        qacc = __builtin_amdgcn_mfma_f32_32x32x16_f16(wq0, __builtin_bit_cast(h8, b0u), qacc, 0, 0, 0);
        qacc = __builtin_amdgcn_mfma_f32_32x32x16_f16(wq1, __builtin_bit_cast(h8, b1u), qacc, 0, 0, 0);

        float v[6];
        #pragma unroll
        for (int r = 0; r < 6; ++r) v[r] = qacc[r] * inv;
        unsigned* drow = (unsigned*)(dst + (tcol + RH) * RS);
        drow[hi * 2 + 0] = pk(v[0], v[1]);
        drow[hi * 2 + 1] = pk(v[2], v[3]);
        if (!hi) drow[4] = pk(v[4], v[5]);
    }
}

// ---------------------------------------------------------------------------
__global__ __launch_bounds__(256, 4) void enc_dec_kernel(
    const float* __restrict__ x,
    const float* __restrict__ w1, const float* __restrict__ b1,
    const float* __restrict__ b2, const float* __restrict__ b3,
    const float* __restrict__ d1b, const float* __restrict__ d2b,
    const uint4* __restrict__ wtab, const unsigned* __restrict__ c2tab,
    _Float16* __restrict__ flat)
{
    __shared__ float xbuf[XS];
    __shared__ _Float16 bufA[NROW * RS];
    __shared__ _Float16 bufB[NROW * RS];
    __shared__ float sc2[32];
    __shared__ float sbias[4][16];

    const int tid = threadIdx.x;
    const int b = blockIdx.x;

    {
        uint4 z; z.x = 0; z.y = 0; z.z = 0; z.w = 0;
        uint4* pa = (uint4*)bufA;
        uint4* pb = (uint4*)bufB;
        for (int i = tid; i < NROW * RS / 8; i += 256) { pa[i] = z; pb[i] = z; }
    }
    if (tid < 8) xbuf[(tid < 4) ? tid : TT + tid] = 0.f;
    if (tid < 128)
        *(float4*)&xbuf[XH + tid * 4] = ((const float4*)(x + (size_t)b * TT))[tid];
    if (tid >= 128 && tid < 160) sc2[tid - 128] = __uint_as_float(c2tab[tid - 128]);
    if (tid >= 160 && tid < 224) {
        int s = (tid - 160) >> 4, i = (tid - 160) & 15;
        float v = 0.f;
        if (i < 10) v = (s == 0) ? b2[i] : (s == 1) ? b3[i] : (s == 2) ? d1b[i] : d2b[i];
        sbias[s][i] = v;
    }
    __syncthreads();

    // conv1 (scalar): 1->5ch k=3 relu
    {
        const int t0 = tid * 2;
        float xm = xbuf[XH + t0 - 1], x0v = xbuf[XH + t0];
        float x1v = xbuf[XH + t0 + 1], x2v = xbuf[XH + t0 + 2];
        h8 r0 = {}; h8 r1 = {};
        #pragma unroll
        for (int o = 0; o < 5; ++o) {
            float k0 = w1[o * 3], k1 = w1[o * 3 + 1], k2 = w1[o * 3 + 2], bb = b1[o];
            float a0 = fmaf(k0, xm,  fmaf(k1, x0v, fmaf(k2, x1v, bb)));
            float a1 = fmaf(k0, x0v, fmaf(k1, x1v, fmaf(k2, x2v, bb)));
            r0[o] = (_Float16)fmaxf(a0, 0.f);
            r1[o] = (_Float16)fmaxf(a1, 0.f);
        }
        *(h8*)&bufA[(t0 + RH) * RS] = r0;
        *(h8*)&bufA[(t0 + 1 + RH) * RS] = r1;
    }
    __syncthreads();

    conv_stage<5, 2, 0>(bufA, bufB, wtab, 0,    sbias[0]);   // conv2
    __syncthreads();
    conv_stage<7, 3, 1>(bufB, bufA, wtab, 320,  sbias[1]);   // conv3 (tanh)
    __syncthreads();
    vq_stage(bufA, bufB, wtab, sc2);                          // VQ
    __syncthreads();
    conv_stage<5, 2, 0>(bufB, bufA, wtab, 768,  sbias[2]);   // d1
    __syncthreads();
    conv_stage_flat<5, 2>(bufA, flat + (size_t)b * (10 * TT),
                          wtab, 1088, sbias[3]);              // d2 -> global
}

// ---------------------------------------------------------------------------
// FC via f16 MFMA. BM=64, BN=32, grid 256 (all CUs), 4 waves; each wave does
// the 64x32 tile over a K-quarter; cross-wave reduce + bias + tanh epilogue.
__global__ __launch_bounds__(256, 1) void fc_mfma_kernel(
    const _Float16* __restrict__ A,
    const _Float16* __restrict__ W,
    const float* __restrict__ bias,
    float* __restrict__ out)
{
    __shared__ __align__(16) unsigned char smem[49152];

    const int tid  = threadIdx.x;
    const int lane = tid & 63;
    const int w    = tid >> 6;

    const int bid = blockIdx.x;
    const int swz = (bid & 7) * 32 + (bid >> 3);   // 8 XCDs x 32 wgs
    const int m0 = (swz >> 4) * 64;                // 16 m-tiles
    const int n0 = (swz & 15) * 32;                // 16 n-tiles

    const int l31 = lane & 31;
    const int lh  = lane >> 5;
    const int rl16 = lane >> 4;
    const int c_lds = lane & 15;

    f32x16 acc0 = {}, acc1 = {};

    const _Float16* Asrc = A + (size_t)m0 * K_FC;
    const _Float16* Wsrc = W + (size_t)n0 * K_FC;

    auto stage = [&](int buf, int s) {
        unsigned char* Ad = smem + buf * 24576;
        unsigned char* Bd = Ad + 16384;
        const int k0 = s * 128;
        #pragma unroll
        for (int j = 0; j < 4; ++j) {
            const int i = w * 4 + j;               // 16 issues: A rows 0..63
            const int rloc = 4 * i + rl16;
            const int csrc = c_lds ^ (rloc & 7);
            __builtin_amdgcn_global_load_lds(
                (GAS*)(Asrc + (size_t)rloc * K_FC + k0 + csrc * 8),
                (LAS*)(Ad + i * 1024), 16, 0, 0);
        }
        #pragma unroll
        for (int j = 0; j < 2; ++j) {
            const int i = w * 2 + j;               // 8 issues: W rows 0..31
            const int rloc = 4 * i + rl16;
            const int csrc = c_lds ^ (rloc & 7);
            __builtin_amdgcn_global_load_lds(
                (GAS*)(Wsrc + (size_t)rloc * K_FC + k0 + csrc * 8),
                (LAS*)(Bd + i * 1024), 16, 0, 0);
        }
    };

    stage(0, 0);
    __syncthreads();

    for (int s = 0; s < 40; ++s) {
        const int cur = s & 1;
        if (s + 1 < 40) stage(cur ^ 1, s + 1);

        const unsigned char* Ab = smem + cur * 24576;
        const unsigned char* Bb = Ab + 16384;
        #pragma unroll
        for (int ks = 0; ks < 2; ++ks) {
            const int chunk = w * 4 + ks * 2 + lh;
            const int swzo  = ((chunk ^ (lane & 7)) << 4);
            h8 af0 = *(const h8*)(Ab +        l31 * 256 + swzo);
            h8 af1 = *(const h8*)(Ab + 8192 + l31 * 256 + swzo);
            h8 bf  = *(const h8*)(Bb +        l31 * 256 + swzo);
            acc0 = __builtin_amdgcn_mfma_f32_32x32x16_f16(af0, bf, acc0, 0, 0, 0);
            acc1 = __builtin_amdgcn_mfma_f32_32x32x16_f16(af1, bf, acc1, 0, 0, 0);
        }
        __syncthreads();
    }

    // cross-wave reduce + bias + tanh: red[w][mf][rq][lane][rr]
    float* red = (float*)smem;
    {
        float* base = red + w * 2048;
        #pragma unroll
        for (int rq = 0; rq < 4; ++rq) {
            float4 v;
            v.x = acc0[rq*4+0]; v.y = acc0[rq*4+1]; v.z = acc0[rq*4+2]; v.w = acc0[rq*4+3];
            *(float4*)&base[rq * 256 + lane * 4] = v;
            v.x = acc1[rq*4+0]; v.y = acc1[rq*4+1]; v.z = acc1[rq*4+2]; v.w = acc1[rq*4+3];
            *(float4*)&base[1024 + rq * 256 + lane * 4] = v;
        }
    }
    __syncthreads();
    {
        const int lo   = tid & 63;
        const int mf   = (tid >> 6) & 1;
        const int half = tid >> 7;
        const int n    = lo & 31;
        const float bv = bias[n0 + n];
        #pragma unroll
        for (int q = 0; q < 2; ++q) {
            const int rq = half * 2 + q;
            const int idx = mf * 1024 + rq * 256 + lo * 4;
            float4 s0 = *(const float4*)&red[idx];
            float4 s1 = *(const float4*)&red[2048 + idx];
            float4 s2 = *(const float4*)&red[4096 + idx];
            float4 s3 = *(const float4*)&red[6144 + idx];
            #pragma unroll
            for (int rr = 0; rr < 4; ++rr) {
                float sum = ((const float*)&s0)[rr] + ((const float*)&s1)[rr]
                          + ((const float*)&s2)[rr] + ((const float*)&s3)[rr];
                const int m = mf * 32 + rr + 8 * rq + 4 * (lo >> 5);
                out[(size_t)(m0 + m) * 512 + n0 + n] = fast_tanh(sum + bv);
            }
        }
    }
}

extern "C" void kernel_launch(void* const* d_in, const int* in_sizes, int n_in,
                              void* d_out, int out_size, void* d_ws, size_t ws_size,
                              hipStream_t stream) {
    const float* x    = (const float*)d_in[0];
    const float* w1   = (const float*)d_in[1];
    const float* b1   = (const float*)d_in[2];
    const float* w2   = (const float*)d_in[3];
    const float* b2   = (const float*)d_in[4];
    const float* w3   = (const float*)d_in[5];
    const float* b3   = (const float*)d_in[6];
    const float* code = (const float*)d_in[7];
    const float* d1w  = (const float*)d_in[8];
    const float* d1b  = (const float*)d_in[9];
    const float* d2w  = (const float*)d_in[10];
    const float* d2b  = (const float*)d_in[11];
    const float* fcw  = (const float*)d_in[12];
    const float* fcb  = (const float*)d_in[13];
    float* out = (float*)d_out;

    _Float16* flat_h = (_Float16*)d_ws;                             // 10.0 MB
    _Float16* fcw_h  = (_Float16*)((char*)d_ws + 10485760);         //  5.0 MB
    uint4*    wtab   = (uint4*)((char*)d_ws + 15728640);            // 25.6 KB
    unsigned* c2tab  = (unsigned*)((char*)d_ws + 15728640 + 25600); // 128 B

    const int Bsz = in_sizes[0] / TT;   // 1024

    prep_kernel<<<1287, 256, 0, stream>>>(fcw, fcw_h, w2, w3, d1w, d2w, code,
                                          wtab, c2tab);
    enc_dec_kernel<<<Bsz, 256, 0, stream>>>(x, w1, b1, b2, b3, d1b, d2b,
                                            wtab, c2tab, flat_h);
    fc_mfma_kernel<<<256, 256, 0, stream>>>(flat_h, fcw_h, fcb, out);
}